// Round 6
// baseline (143.205 us; speedup 1.0000x reference)
//
#include <hip/hip_runtime.h>
#include <cstdint>
#include <type_traits>

// GPT MHA forward. B=2, T=2048, C=1024, H=16, d=64.
// cast x->bf16 | transpose weights (wq pre-scaled 0.125*log2e) | bias concat
// | QKV GEMM (gload_lds, XCD swizzle) | V-transpose | causal flash attn
//   (4 waves x 32 q-rows, XOR-swizzled K/V/P LDS, swapped QK^T, exp2 softmax,
//    defer-max, async-STAGE, bh->XCD pinning, masked-tile skip) | out-proj GEMM.

#define TSEQ  2048
#define BATCH 2
#define CDIM  1024
#define NHEAD 16
#define DHEAD 64
#define NROWS (BATCH * TSEQ)  // 4096

// 0.125 (1/sqrt(d)) * log2(e): folded into wq/bq so softmax uses exp2
#define QSCALE 0.1803368801111244f

typedef unsigned short u16;
typedef u16   u16x8  __attribute__((ext_vector_type(8)));
typedef __bf16 bf16x8 __attribute__((ext_vector_type(8)));
typedef __bf16 bf16x2 __attribute__((ext_vector_type(2)));
typedef float f32x4  __attribute__((ext_vector_type(4)));

typedef const __attribute__((address_space(1))) void* gas_vp;
typedef __attribute__((address_space(3))) void* las_vp;

__device__ __forceinline__ u16 f2bf(float f) {
  return __builtin_bit_cast(u16, (__bf16)f);
}

__device__ __forceinline__ uint32_t pack2bf(float a, float b) {
  bf16x2 v;
  v[0] = (__bf16)a;
  v[1] = (__bf16)b;
  return __builtin_bit_cast(uint32_t, v);
}

__device__ __forceinline__ f32x4 mfma_bf16(u16x8 a, u16x8 b, f32x4 c) {
  return __builtin_amdgcn_mfma_f32_16x16x32_bf16(
      __builtin_bit_cast(bf16x8, a), __builtin_bit_cast(bf16x8, b), c, 0, 0, 0);
}

__device__ __forceinline__ void gload16(const u16* g, u16* l) {
  __builtin_amdgcn_global_load_lds((gas_vp)g, (las_vp)l, 16, 0, 0);
}

// ---------------- prep kernels ----------------

__global__ __launch_bounds__(256) void cast_x_kernel(const float* __restrict__ in,
                                                     u16* __restrict__ out, int n4) {
  int i = blockIdx.x * 256 + threadIdx.x;
  if (i < n4) {
    float4 v = ((const float4*)in)[i];
    ((uint2*)out)[i] = make_uint2(pack2bf(v.x, v.y), pack2bf(v.z, v.w));
  }
}

__global__ __launch_bounds__(256) void transpose_cast_kernel(
    const float* __restrict__ w0, const float* __restrict__ w1,
    const float* __restrict__ w2, const float* __restrict__ w3,
    u16* __restrict__ outQKV, u16* __restrict__ outO) {
  __shared__ float tile[32][33];
  const int m = blockIdx.z;
  const float* w = (m == 0) ? w0 : (m == 1) ? w1 : (m == 2) ? w2 : w3;
  const float scale = (m == 0) ? QSCALE : 1.0f;
  u16* out = (m < 3) ? (outQKV + (size_t)m * CDIM * CDIM) : outO;
  const int n0 = blockIdx.x * 32;
  const int k0 = blockIdx.y * 32;
  const int tx = threadIdx.x, ty = threadIdx.y;  // block (32, 8)
#pragma unroll
  for (int i = 0; i < 4; ++i)
    tile[ty + i * 8][tx] = w[(size_t)(k0 + ty + i * 8) * CDIM + n0 + tx];
  __syncthreads();
#pragma unroll
  for (int i = 0; i < 4; ++i)
    out[(size_t)(n0 + ty + i * 8) * CDIM + k0 + tx] = f2bf(tile[tx][ty + i * 8] * scale);
}

__global__ __launch_bounds__(256) void bias_concat_kernel(const float* __restrict__ bq,
                                                          const float* __restrict__ bk,
                                                          const float* __restrict__ bv,
                                                          float* __restrict__ out) {
  int i = blockIdx.x * 256 + threadIdx.x;
  if (i < 3 * CDIM) {
    float v = (i < CDIM) ? bq[i] * QSCALE
            : (i < 2 * CDIM) ? bk[i - CDIM] : bv[i - 2 * CDIM];
    out[i] = v;
  }
}

// V part of QKV [B*T][3C] -> Vt [B][H][D][T]
__global__ __launch_bounds__(256) void vtrans_kernel(const u16* __restrict__ QKV,
                                                     u16* __restrict__ Vt) {
  __shared__ u16 tile[32][33];
  const int bh = blockIdx.z;
  const int b = bh >> 4, h = bh & 15;
  const int t0 = blockIdx.x * 32, d0 = blockIdx.y * 32;
  const int tx = threadIdx.x, ty = threadIdx.y;  // block (32, 8)
#pragma unroll
  for (int i = 0; i < 4; ++i)
    tile[ty + i * 8][tx] =
        QKV[(size_t)(b * TSEQ + t0 + ty + i * 8) * (3 * CDIM) + 2 * CDIM + h * DHEAD + d0 + tx];
  __syncthreads();
#pragma unroll
  for (int i = 0; i < 4; ++i)
    Vt[(size_t)((b * NHEAD + h) * DHEAD + d0 + ty + i * 8) * TSEQ + t0 + tx] =
        tile[tx][ty + i * 8];
}

// ---------------- GEMM: C[M][N] = A[M][K] @ Bt[N][K]^T + bias ----------------
// 128x128 tile, BK=32, 4 waves, global_load_lds staging; 1D grid + XCD swizzle.

template <typename OutT>
__global__ __launch_bounds__(256) void gemm_bt_kernel(
    const u16* __restrict__ A, const u16* __restrict__ Bt,
    const float* __restrict__ bias, OutT* __restrict__ C,
    int M, int N, int K, int mblocks) {
  __shared__ u16 As[128 * 32];
  __shared__ u16 Bs[128 * 32];
  const int nwg = gridDim.x;
  const int lid = blockIdx.x;
  const int swz = (lid & 7) * (nwg >> 3) + (lid >> 3);
  const int m0 = (swz % mblocks) * 128;
  const int n0 = (swz / mblocks) * 128;

  const int t = threadIdx.x;
  const int lane = t & 63;
  const int w = t >> 6;
  const int wr = w >> 1, wc = w & 1;
  const int l15 = lane & 15;
  const int lg = lane >> 4;
  const int srow = lane >> 2;
  const int scol = (lane & 3) * 8;

  f32x4 acc[4][4];
#pragma unroll
  for (int i = 0; i < 4; ++i)
#pragma unroll
    for (int j = 0; j < 4; ++j) acc[i][j] = f32x4{0.f, 0.f, 0.f, 0.f};

  for (int k0 = 0; k0 < K; k0 += 32) {
    __syncthreads();
#pragma unroll
    for (int ci = 0; ci < 2; ++ci) {
      const int chunk = w * 2 + ci;
      const int grow = chunk * 16 + srow;
      gload16(&A[(size_t)(m0 + grow) * K + k0 + scol], &As[chunk * 512]);
      gload16(&Bt[(size_t)(n0 + grow) * K + k0 + scol], &Bs[chunk * 512]);
    }
    __syncthreads();
    u16x8 af[4], bf[4];
#pragma unroll
    for (int i = 0; i < 4; ++i)
      af[i] = *(const u16x8*)(&As[(wr * 64 + i * 16 + l15) * 32 + lg * 8]);
#pragma unroll
    for (int j = 0; j < 4; ++j)
      bf[j] = *(const u16x8*)(&Bs[(wc * 64 + j * 16 + l15) * 32 + lg * 8]);
#pragma unroll
    for (int i = 0; i < 4; ++i)
#pragma unroll
      for (int j = 0; j < 4; ++j) acc[i][j] = mfma_bf16(af[i], bf[j], acc[i][j]);
  }

#pragma unroll
  for (int j = 0; j < 4; ++j) {
    int col = n0 + wc * 64 + j * 16 + l15;
    float bv = bias[col];
#pragma unroll
    for (int i = 0; i < 4; ++i) {
#pragma unroll
      for (int r = 0; r < 4; ++r) {
        int row = m0 + wr * 64 + i * 16 + lg * 4 + r;
        float val = acc[i][j][r] + bv;
        if constexpr (std::is_same<OutT, float>::value)
          C[(size_t)row * N + col] = val;
        else
          C[(size_t)row * N + col] = f2bf(val);
      }
    }
  }
}

// ---------------- causal flash attention (4-wave, 32 q/wave, swizzled) -----
// 512 blocks x 4 waves; block owns 128 q-rows (32/wave); KVBLK=64 staged in
// XOR-swizzled LDS ([64][64 u16], byte ^= (row&7)<<4). Each K/V LDS fragment
// feeds 2 q-frags (halved LDS reads per FLOP). bh->XCD pinning + LPT.
// Swapped QK^T, exp2 softmax, vote-gated defer-max, async-STAGE, masked-tile
// compute skip.

__global__ __launch_bounds__(256) void attn_kernel(const u16* __restrict__ QKV,
                                                   const u16* __restrict__ Vt,
                                                   u16* __restrict__ O) {
  __shared__ u16 Ks[64 * 64];
  __shared__ u16 Vs[64 * 64];       // V^T tile [d=64][k=64]
  __shared__ u16 Ps[4 * 32 * 64];   // per-wave 32-row P / O staging

  char* KsB = (char*)Ks;
  char* VsB = (char*)Vs;

  const int t = threadIdx.x;
  const int lane = t & 63;
  const int w = t >> 6;             // 0..3
  const int l15 = lane & 15, lg = lane >> 4;
  const int xorv = (l15 & 7) << 4;  // row-XOR for all rows this lane touches

  // bh->XCD pinning + LPT: xcd serves bh in {xcd, 8+xcd, 16+xcd, 24+xcd};
  // heaviest q-tile (qt=15) per bh dispatches first.
  const int lid = blockIdx.x;       // 0..511
  const int xcd = lid & 7;
  const int m = lid >> 3;           // 0..63
  const int bh = (m & 3) * 8 + xcd; // 0..31
  const int qt = 15 - (m >> 2);     // 0..15, heavy first
  const int b = bh >> 4, h = bh & 15;
  const int q0 = qt * 128;
  const int qrow = q0 + w * 32;     // wave's 32 q-rows
  const int nkt = (qt + 1) * 2;     // k-tiles of 64

  const size_t RS = 3 * CDIM;
  const u16* Qp  = QKV + (size_t)(b * TSEQ) * RS + h * DHEAD;
  const u16* Kp  = Qp + CDIM;
  const u16* Vgp = Vt + (size_t)(b * NHEAD + h) * DHEAD * TSEQ;
  char* PwB = (char*)&Ps[w * 32 * 64];

  // Q fragments (B-operand): row q = qrow+qq*16+l15, k elems lg*8..
  u16x8 qf[2][2];  // [c][qq]
#pragma unroll
  for (int qq = 0; qq < 2; ++qq)
#pragma unroll
    for (int c = 0; c < 2; ++c)
      qf[c][qq] =
          *(const u16x8*)(&Qp[(size_t)(qrow + qq * 16 + l15) * RS + c * 32 + lg * 8]);

  f32x4 acc[4][2];
#pragma unroll
  for (int g = 0; g < 4; ++g)
#pragma unroll
    for (int qq = 0; qq < 2; ++qq) acc[g][qq] = f32x4{0.f, 0.f, 0.f, 0.f};
  float m_run[2] = {-3e38f, -3e38f};
  float l_part[2] = {0.f, 0.f};

  // staging: 256 threads cover rows {sr, sr+32} x chunk sch for K and V
  const int sr = t >> 3;            // 0..31
  const int sch = t & 7;            // 16B chunk 0..7
  const int swA = sr * 128 + ((sch * 16) ^ ((sr & 7) << 4));  // swizzled LDS byte

  // T14 prologue: first K/V tile -> regs
  u16x8 kreg[2], vreg[2];
  kreg[0] = *(const u16x8*)(&Kp[(size_t)sr * RS + sch * 8]);
  kreg[1] = *(const u16x8*)(&Kp[(size_t)(sr + 32) * RS + sch * 8]);
  vreg[0] = *(const u16x8*)(&Vgp[(size_t)sr * TSEQ + sch * 8]);
  vreg[1] = *(const u16x8*)(&Vgp[(size_t)(sr + 32) * TSEQ + sch * 8]);

  for (int kb = 0; kb < nkt; ++kb) {
    __syncthreads();  // all waves done reading previous tile
    *(u16x8*)(KsB + swA) = kreg[0];
    *(u16x8*)(KsB + swA + 32 * 128) = kreg[1];  // (sr+32)&7 == sr&7
    *(u16x8*)(VsB + swA) = vreg[0];
    *(u16x8*)(VsB + swA + 32 * 128) = vreg[1];
    __syncthreads();

    // issue next-tile loads; latency hides under compute below
    if (kb + 1 < nkt) {
      kreg[0] = *(const u16x8*)(&Kp[(size_t)((kb + 1) * 64 + sr) * RS + sch * 8]);
      kreg[1] = *(const u16x8*)(&Kp[(size_t)((kb + 1) * 64 + sr + 32) * RS + sch * 8]);
      vreg[0] = *(const u16x8*)(&Vgp[(size_t)sr * TSEQ + (kb + 1) * 64 + sch * 8]);
      vreg[1] = *(const u16x8*)(&Vgp[(size_t)(sr + 32) * TSEQ + (kb + 1) * 64 + sch * 8]);
    }

    if (kb * 64 > qrow + 31) continue;  // fully-masked tile: stage+barrier only

    // S^T[k][q]: rows k = f*16+lg*4+r, col q = l15, per qq
    f32x4 sfr[4][2];
    __builtin_amdgcn_s_setprio(1);
#pragma unroll
    for (int f = 0; f < 4; ++f) {
      const char* rowp = KsB + (f * 16 + l15) * 128;
      u16x8 k0 = *(const u16x8*)(rowp + ((lg * 16) ^ xorv));
      u16x8 k1 = *(const u16x8*)(rowp + ((64 + lg * 16) ^ xorv));
#pragma unroll
      for (int qq = 0; qq < 2; ++qq) {
        f32x4 s = mfma_bf16(k0, qf[0][qq], f32x4{0.f, 0.f, 0.f, 0.f});
        sfr[f][qq] = mfma_bf16(k1, qf[1][qq], s);
      }
    }
    __builtin_amdgcn_s_setprio(0);

    if (kb * 64 + 63 > qrow) {  // causal mask (wave-uniform predicate)
#pragma unroll
      for (int qq = 0; qq < 2; ++qq) {
        const int q_abs = qrow + qq * 16 + l15;
#pragma unroll
        for (int f = 0; f < 4; ++f) {
          const int kbase = kb * 64 + f * 16 + lg * 4;
#pragma unroll
          for (int r = 0; r < 4; ++r)
            if (kbase + r > q_abs) sfr[f][qq][r] = -1e9f;
        }
      }
    }

    // per-qq in-lane max; wave vote gates rescale (T13, THR=8)
    float mx[2];
#pragma unroll
    for (int qq = 0; qq < 2; ++qq) {
      float v = sfr[0][qq][0];
#pragma unroll
      for (int f = 0; f < 4; ++f)
#pragma unroll
        for (int r = 0; r < 4; ++r) v = fmaxf(v, sfr[f][qq][r]);
      mx[qq] = v;
    }
    if (__any((mx[0] > m_run[0] + 8.f) || (mx[1] > m_run[1] + 8.f))) {
#pragma unroll
      for (int qq = 0; qq < 2; ++qq) {
        float gm = mx[qq];
        gm = fmaxf(gm, __shfl_xor(gm, 16));
        gm = fmaxf(gm, __shfl_xor(gm, 32));
        float mnew = fmaxf(m_run[qq], gm);
        float fac = exp2f(m_run[qq] - mnew);
        m_run[qq] = mnew;
        l_part[qq] *= fac;
#pragma unroll
        for (int g = 0; g < 4; ++g) acc[g][qq] *= fac;
      }
    }

    // P = exp2(S - m); per-lane partial l; packed u32 -> swizzled Pw
#pragma unroll
    for (int qq = 0; qq < 2; ++qq) {
      char* pb = PwB + (qq * 16 + l15) * 128;  // (qq*16+l15)&7 == l15&7
      float ls = 0.f;
#pragma unroll
      for (int f = 0; f < 4; ++f) {
        float p0 = exp2f(sfr[f][qq][0] - m_run[qq]);
        float p1 = exp2f(sfr[f][qq][1] - m_run[qq]);
        float p2 = exp2f(sfr[f][qq][2] - m_run[qq]);
        float p3 = exp2f(sfr[f][qq][3] - m_run[qq]);
        ls += (p0 + p1) + (p2 + p3);
        const int boff = (f * 32 + lg * 8) ^ xorv;  // xorv bits>=4, 8B align kept
        *(uint32_t*)(pb + boff) = pack2bf(p0, p1);
        *(uint32_t*)(pb + boff + 4) = pack2bf(p2, p3);
      }
      l_part[qq] += ls;
    }

    // O^T += mfma(V^T, P)
    __builtin_amdgcn_s_setprio(1);
#pragma unroll
    for (int c = 0; c < 2; ++c) {
      const int coff = (c * 64 + lg * 16) ^ xorv;
      u16x8 pf0 = *(const u16x8*)(PwB + (l15) * 128 + coff);
      u16x8 pf1 = *(const u16x8*)(PwB + (16 + l15) * 128 + coff);
#pragma unroll
      for (int g = 0; g < 4; ++g) {
        u16x8 vf = *(const u16x8*)(VsB + (g * 16 + l15) * 128 + coff);
        acc[g][0] = mfma_bf16(vf, pf0, acc[g][0]);
        acc[g][1] = mfma_bf16(vf, pf1, acc[g][1]);
      }
    }
    __builtin_amdgcn_s_setprio(0);
  }

  // epilogue: reduce l across lane-groups, normalize, un-transpose via Pw
  float inv[2];
#pragma unroll
  for (int qq = 0; qq < 2; ++qq) {
    float lt = l_part[qq];
    lt += __shfl_xor(lt, 16);
    lt += __shfl_xor(lt, 32);
    inv[qq] = 1.f / lt;
  }
#pragma unroll
  for (int qq = 0; qq < 2; ++qq) {
    char* pb = PwB + (qq * 16 + l15) * 128;
#pragma unroll
    for (int g = 0; g < 4; ++g) {
      const int boff = (g * 32 + lg * 8) ^ xorv;
      *(uint32_t*)(pb + boff) = pack2bf(acc[g][qq][0] * inv[qq], acc[g][qq][1] * inv[qq]);
      *(uint32_t*)(pb + boff + 4) = pack2bf(acc[g][qq][2] * inv[qq], acc[g][qq][3] * inv[qq]);
    }
  }
#pragma unroll
  for (int i = 0; i < 4; ++i) {
    const int rl = i * 8 + (lane >> 3);  // 0..31
    const int ch = lane & 7;
    u16x8 vv = *(const u16x8*)(PwB + rl * 128 + ((ch * 16) ^ ((rl & 7) << 4)));
    *(u16x8*)(&O[(size_t)(b * TSEQ + qrow + rl) * CDIM + h * DHEAD + ch * 8]) = vv;
  }
}

// ---------------- launch ----------------

extern "C" void kernel_launch(void* const* d_in, const int* in_sizes, int n_in,
                              void* d_out, int out_size, void* d_ws, size_t ws_size,
                              hipStream_t stream) {
  const float* x  = (const float*)d_in[0];
  const float* wq = (const float*)d_in[1];
  const float* bq = (const float*)d_in[2];
  const float* wk = (const float*)d_in[3];
  const float* bk = (const float*)d_in[4];
  const float* wv = (const float*)d_in[5];
  const float* bv = (const float*)d_in[6];
  const float* wo = (const float*)d_in[7];
  const float* bo = (const float*)d_in[8];
  float* out = (float*)d_out;

  char* ws = (char*)d_ws;
  u16*  xb      = (u16*)(ws);                 // 8MB; dead after QKV GEMM
  u16*  Vtg     = (u16*)(ws);                 // aliases xb (written after)
  u16*  wqkvT   = (u16*)(ws + (8ll << 20));
  u16*  woT     = (u16*)(ws + (14ll << 20));
  u16*  QKV     = (u16*)(ws + (16ll << 20));
  u16*  Obuf    = (u16*)(ws + (40ll << 20));
  float* biasqkv = (float*)(ws + (48ll << 20));

  cast_x_kernel<<<(NROWS * CDIM / 4 + 255) / 256, 256, 0, stream>>>(x, xb, NROWS * CDIM / 4);
  {
    dim3 g(CDIM / 32, CDIM / 32, 4), blk(32, 8);
    transpose_cast_kernel<<<g, blk, 0, stream>>>(wq, wk, wv, wo, wqkvT, woT);
  }
  bias_concat_kernel<<<12, 256, 0, stream>>>(bq, bk, bv, biasqkv);
  gemm_bt_kernel<u16><<<(NROWS / 128) * ((3 * CDIM) / 128), 256, 0, stream>>>(
      xb, wqkvT, biasqkv, QKV, NROWS, 3 * CDIM, CDIM, NROWS / 128);
  {
    dim3 g(TSEQ / 32, DHEAD / 32, BATCH * NHEAD), blk(32, 8);
    vtrans_kernel<<<g, blk, 0, stream>>>(QKV, Vtg);
  }
  attn_kernel<<<512, 256, 0, stream>>>(QKV, Vtg, Obuf);
  gemm_bt_kernel<float><<<(NROWS / 128) * (CDIM / 128), 256, 0, stream>>>(
      Obuf, woT, bo, out, NROWS, CDIM, CDIM, NROWS / 128);
}

// Round 7
// 133.827 us; speedup vs baseline: 1.0701x; 1.0701x over previous
//
#include <hip/hip_runtime.h>
#include <cstdint>
#include <type_traits>

// GPT MHA forward. B=2, T=2048, C=1024, H=16, d=64.
// cast x->bf16 | transpose weights (wq pre-scaled 0.125*log2e) | bias concat
// | QKV GEMM (gload_lds, XCD swizzle) | V-transpose | causal flash attn
//   (8 waves x 16 q-rows, XOR-swizzled K/V/P LDS, swapped QK^T, exp2 softmax,
//    defer-max, async-STAGE, bh->XCD pinning, masked-tile skip) | out-proj GEMM.

#define TSEQ  2048
#define BATCH 2
#define CDIM  1024
#define NHEAD 16
#define DHEAD 64
#define NROWS (BATCH * TSEQ)  // 4096

// 0.125 (1/sqrt(d)) * log2(e): folded into wq/bq so softmax uses exp2
#define QSCALE 0.1803368801111244f

typedef unsigned short u16;
typedef u16   u16x8  __attribute__((ext_vector_type(8)));
typedef __bf16 bf16x8 __attribute__((ext_vector_type(8)));
typedef __bf16 bf16x2 __attribute__((ext_vector_type(2)));
typedef float f32x4  __attribute__((ext_vector_type(4)));

typedef const __attribute__((address_space(1))) void* gas_vp;
typedef __attribute__((address_space(3))) void* las_vp;

__device__ __forceinline__ u16 f2bf(float f) {
  return __builtin_bit_cast(u16, (__bf16)f);
}

__device__ __forceinline__ uint32_t pack2bf(float a, float b) {
  bf16x2 v;
  v[0] = (__bf16)a;
  v[1] = (__bf16)b;
  return __builtin_bit_cast(uint32_t, v);
}

__device__ __forceinline__ f32x4 mfma_bf16(u16x8 a, u16x8 b, f32x4 c) {
  return __builtin_amdgcn_mfma_f32_16x16x32_bf16(
      __builtin_bit_cast(bf16x8, a), __builtin_bit_cast(bf16x8, b), c, 0, 0, 0);
}

__device__ __forceinline__ void gload16(const u16* g, u16* l) {
  __builtin_amdgcn_global_load_lds((gas_vp)g, (las_vp)l, 16, 0, 0);
}

// ---------------- prep kernels ----------------

__global__ __launch_bounds__(256) void cast_x_kernel(const float* __restrict__ in,
                                                     u16* __restrict__ out, int n4) {
  int i = blockIdx.x * 256 + threadIdx.x;
  if (i < n4) {
    float4 v = ((const float4*)in)[i];
    ((uint2*)out)[i] = make_uint2(pack2bf(v.x, v.y), pack2bf(v.z, v.w));
  }
}

__global__ __launch_bounds__(256) void transpose_cast_kernel(
    const float* __restrict__ w0, const float* __restrict__ w1,
    const float* __restrict__ w2, const float* __restrict__ w3,
    u16* __restrict__ outQKV, u16* __restrict__ outO) {
  __shared__ float tile[32][33];
  const int m = blockIdx.z;
  const float* w = (m == 0) ? w0 : (m == 1) ? w1 : (m == 2) ? w2 : w3;
  const float scale = (m == 0) ? QSCALE : 1.0f;
  u16* out = (m < 3) ? (outQKV + (size_t)m * CDIM * CDIM) : outO;
  const int n0 = blockIdx.x * 32;
  const int k0 = blockIdx.y * 32;
  const int tx = threadIdx.x, ty = threadIdx.y;  // block (32, 8)
#pragma unroll
  for (int i = 0; i < 4; ++i)
    tile[ty + i * 8][tx] = w[(size_t)(k0 + ty + i * 8) * CDIM + n0 + tx];
  __syncthreads();
#pragma unroll
  for (int i = 0; i < 4; ++i)
    out[(size_t)(n0 + ty + i * 8) * CDIM + k0 + tx] = f2bf(tile[tx][ty + i * 8] * scale);
}

__global__ __launch_bounds__(256) void bias_concat_kernel(const float* __restrict__ bq,
                                                          const float* __restrict__ bk,
                                                          const float* __restrict__ bv,
                                                          float* __restrict__ out) {
  int i = blockIdx.x * 256 + threadIdx.x;
  if (i < 3 * CDIM) {
    float v = (i < CDIM) ? bq[i] * QSCALE
            : (i < 2 * CDIM) ? bk[i - CDIM] : bv[i - 2 * CDIM];
    out[i] = v;
  }
}

// V part of QKV [B*T][3C] -> Vt [B][H][D][T]
__global__ __launch_bounds__(256) void vtrans_kernel(const u16* __restrict__ QKV,
                                                     u16* __restrict__ Vt) {
  __shared__ u16 tile[32][33];
  const int bh = blockIdx.z;
  const int b = bh >> 4, h = bh & 15;
  const int t0 = blockIdx.x * 32, d0 = blockIdx.y * 32;
  const int tx = threadIdx.x, ty = threadIdx.y;  // block (32, 8)
#pragma unroll
  for (int i = 0; i < 4; ++i)
    tile[ty + i * 8][tx] =
        QKV[(size_t)(b * TSEQ + t0 + ty + i * 8) * (3 * CDIM) + 2 * CDIM + h * DHEAD + d0 + tx];
  __syncthreads();
#pragma unroll
  for (int i = 0; i < 4; ++i)
    Vt[(size_t)((b * NHEAD + h) * DHEAD + d0 + ty + i * 8) * TSEQ + t0 + tx] =
        tile[tx][ty + i * 8];
}

// ---------------- GEMM: C[M][N] = A[M][K] @ Bt[N][K]^T + bias ----------------
// 128x128 tile, BK=32, 4 waves, global_load_lds staging; 1D grid + XCD swizzle.

template <typename OutT>
__global__ __launch_bounds__(256) void gemm_bt_kernel(
    const u16* __restrict__ A, const u16* __restrict__ Bt,
    const float* __restrict__ bias, OutT* __restrict__ C,
    int M, int N, int K, int mblocks) {
  __shared__ u16 As[128 * 32];
  __shared__ u16 Bs[128 * 32];
  const int nwg = gridDim.x;
  const int lid = blockIdx.x;
  const int swz = (lid & 7) * (nwg >> 3) + (lid >> 3);
  const int m0 = (swz % mblocks) * 128;
  const int n0 = (swz / mblocks) * 128;

  const int t = threadIdx.x;
  const int lane = t & 63;
  const int w = t >> 6;
  const int wr = w >> 1, wc = w & 1;
  const int l15 = lane & 15;
  const int lg = lane >> 4;
  const int srow = lane >> 2;
  const int scol = (lane & 3) * 8;

  f32x4 acc[4][4];
#pragma unroll
  for (int i = 0; i < 4; ++i)
#pragma unroll
    for (int j = 0; j < 4; ++j) acc[i][j] = f32x4{0.f, 0.f, 0.f, 0.f};

  for (int k0 = 0; k0 < K; k0 += 32) {
    __syncthreads();
#pragma unroll
    for (int ci = 0; ci < 2; ++ci) {
      const int chunk = w * 2 + ci;
      const int grow = chunk * 16 + srow;
      gload16(&A[(size_t)(m0 + grow) * K + k0 + scol], &As[chunk * 512]);
      gload16(&Bt[(size_t)(n0 + grow) * K + k0 + scol], &Bs[chunk * 512]);
    }
    __syncthreads();
    u16x8 af[4], bf[4];
#pragma unroll
    for (int i = 0; i < 4; ++i)
      af[i] = *(const u16x8*)(&As[(wr * 64 + i * 16 + l15) * 32 + lg * 8]);
#pragma unroll
    for (int j = 0; j < 4; ++j)
      bf[j] = *(const u16x8*)(&Bs[(wc * 64 + j * 16 + l15) * 32 + lg * 8]);
#pragma unroll
    for (int i = 0; i < 4; ++i)
#pragma unroll
      for (int j = 0; j < 4; ++j) acc[i][j] = mfma_bf16(af[i], bf[j], acc[i][j]);
  }

#pragma unroll
  for (int j = 0; j < 4; ++j) {
    int col = n0 + wc * 64 + j * 16 + l15;
    float bv = bias[col];
#pragma unroll
    for (int i = 0; i < 4; ++i) {
#pragma unroll
      for (int r = 0; r < 4; ++r) {
        int row = m0 + wr * 64 + i * 16 + lg * 4 + r;
        float val = acc[i][j][r] + bv;
        if constexpr (std::is_same<OutT, float>::value)
          C[(size_t)row * N + col] = val;
        else
          C[(size_t)row * N + col] = f2bf(val);
      }
    }
  }
}

// ---------------- causal flash attention (8-wave, swizzled LDS) ----------------
// R5 structure (512 threads, 8 waves x 16 q-rows, 2 blocks/CU, VGPR~50) with
// R6's validated XOR-swizzle (byte ^= (row&7)<<4 on 128B rows) replacing the
// +8 pad, plus wave-uniform masked-tile compute skip. bh->XCD pinning + LPT.
// Swapped QK^T (mfma(K,Q) -> S^T), exp2 softmax, vote-gated defer-max,
// async-STAGE (regs early, ds_write after barrier).

__global__ __launch_bounds__(512) void attn_kernel(const u16* __restrict__ QKV,
                                                   const u16* __restrict__ Vt,
                                                   u16* __restrict__ O) {
  __shared__ u16 Ks[64 * 64];
  __shared__ u16 Vs[64 * 64];       // V^T tile [d=64][k=64]
  __shared__ u16 Ps[8 * 16 * 64];   // per-wave 16-row P / O staging

  char* KsB = (char*)Ks;
  char* VsB = (char*)Vs;

  const int t = threadIdx.x;
  const int lane = t & 63;
  const int w = t >> 6;             // 0..7
  const int l15 = lane & 15, lg = lane >> 4;
  const int xorv = (l15 & 7) << 4;  // row-XOR for rows ≡ l15 (mod 16)

  // bh->XCD pinning + LPT: xcd serves bh in {xcd, 8+xcd, 16+xcd, 24+xcd};
  // heaviest q-tile (qt=15) per bh dispatches first.
  const int lid = blockIdx.x;       // 0..511
  const int xcd = lid & 7;
  const int m = lid >> 3;           // 0..63
  const int bh = (m & 3) * 8 + xcd; // 0..31
  const int qt = 15 - (m >> 2);     // 0..15, heavy first
  const int b = bh >> 4, h = bh & 15;
  const int q0 = qt * 128;
  const int qrow = q0 + w * 16;     // wave's 16 q-rows
  const int nkt = (qt + 1) * 2;     // k-tiles of 64

  const size_t RS = 3 * CDIM;
  const u16* Qp  = QKV + (size_t)(b * TSEQ) * RS + h * DHEAD;
  const u16* Kp  = Qp + CDIM;
  const u16* Vgp = Vt + (size_t)(b * NHEAD + h) * DHEAD * TSEQ;
  char* PwB = (char*)&Ps[w * 16 * 64];

  // Q fragment (B-operand): row q = qrow+l15, k elems lg*8..
  u16x8 qf[2];
#pragma unroll
  for (int c = 0; c < 2; ++c)
    qf[c] = *(const u16x8*)(&Qp[(size_t)(qrow + l15) * RS + c * 32 + lg * 8]);

  f32x4 acc[4];
#pragma unroll
  for (int g = 0; g < 4; ++g) acc[g] = f32x4{0.f, 0.f, 0.f, 0.f};
  float m_run = -3e38f, l_run = 0.f;

  // staging: 512 threads, 1 chunk each for K and V; swizzled LDS byte addr
  const int sr = t >> 3;            // 0..63
  const int sch = t & 7;            // 16B chunk 0..7
  const int swA = sr * 128 + ((sch * 16) ^ ((sr & 7) << 4));

  // T14 prologue: first K/V tile -> regs
  u16x8 kreg = *(const u16x8*)(&Kp[(size_t)sr * RS + sch * 8]);
  u16x8 vreg = *(const u16x8*)(&Vgp[(size_t)sr * TSEQ + sch * 8]);

  for (int kb = 0; kb < nkt; ++kb) {
    __syncthreads();  // all waves done reading previous tile
    *(u16x8*)(KsB + swA) = kreg;
    *(u16x8*)(VsB + swA) = vreg;
    __syncthreads();

    // issue next-tile loads; latency hides under compute below
    if (kb + 1 < nkt) {
      kreg = *(const u16x8*)(&Kp[(size_t)((kb + 1) * 64 + sr) * RS + sch * 8]);
      vreg = *(const u16x8*)(&Vgp[(size_t)sr * TSEQ + (kb + 1) * 64 + sch * 8]);
    }

    if (kb * 64 > qrow + 15) continue;  // fully-masked tile: stage+barrier only

    // S^T[k][q]: rows k = f*16+lg*4+r, col q = l15 (pre-scaled by QSCALE)
    f32x4 sfr[4];
    __builtin_amdgcn_s_setprio(1);
#pragma unroll
    for (int f = 0; f < 4; ++f) {
      const char* rowp = KsB + (f * 16 + l15) * 128;
      u16x8 k0 = *(const u16x8*)(rowp + ((lg * 16) ^ xorv));
      u16x8 k1 = *(const u16x8*)(rowp + ((64 + lg * 16) ^ xorv));
      f32x4 s = mfma_bf16(k0, qf[0], f32x4{0.f, 0.f, 0.f, 0.f});
      sfr[f] = mfma_bf16(k1, qf[1], s);
    }
    __builtin_amdgcn_s_setprio(0);

    if (kb * 64 + 63 > qrow) {  // causal mask (wave-uniform predicate)
      const int q_abs = qrow + l15;
#pragma unroll
      for (int f = 0; f < 4; ++f) {
        const int kbase = kb * 64 + f * 16 + lg * 4;
#pragma unroll
        for (int r = 0; r < 4; ++r)
          if (kbase + r > q_abs) sfr[f][r] = -1e9f;
      }
    }

    // row-max: in-lane over 16; wave vote gates rescale (T13, THR=8)
    float mx = sfr[0][0];
#pragma unroll
    for (int f = 0; f < 4; ++f)
#pragma unroll
      for (int r = 0; r < 4; ++r) mx = fmaxf(mx, sfr[f][r]);

    if (__any(mx > m_run + 8.f)) {
      float gm = mx;
      gm = fmaxf(gm, __shfl_xor(gm, 16));
      gm = fmaxf(gm, __shfl_xor(gm, 32));
      float mnew = fmaxf(m_run, gm);
      float fac = exp2f(m_run - mnew);
      m_run = mnew;
      l_run *= fac;
#pragma unroll
      for (int g = 0; g < 4; ++g) acc[g] *= fac;
    }

    // P = exp2(S - m); per-lane partial l; packed u32 -> swizzled Pw
    {
      char* pb = PwB + l15 * 128;
      float ls = 0.f;
#pragma unroll
      for (int f = 0; f < 4; ++f) {
        float p0 = exp2f(sfr[f][0] - m_run);
        float p1 = exp2f(sfr[f][1] - m_run);
        float p2 = exp2f(sfr[f][2] - m_run);
        float p3 = exp2f(sfr[f][3] - m_run);
        ls += (p0 + p1) + (p2 + p3);
        const int boff = (f * 32 + lg * 8) ^ xorv;  // stays 8B-aligned
        *(uint32_t*)(pb + boff) = pack2bf(p0, p1);
        *(uint32_t*)(pb + boff + 4) = pack2bf(p2, p3);
      }
      l_run += ls;
    }

    // O^T += mfma(V^T, P)
    __builtin_amdgcn_s_setprio(1);
#pragma unroll
    for (int c = 0; c < 2; ++c) {
      const int coff = (c * 64 + lg * 16) ^ xorv;
      u16x8 pf = *(const u16x8*)(PwB + l15 * 128 + coff);
#pragma unroll
      for (int g = 0; g < 4; ++g) {
        u16x8 vf = *(const u16x8*)(VsB + (g * 16 + l15) * 128 + coff);
        acc[g] = mfma_bf16(vf, pf, acc[g]);
      }
    }
    __builtin_amdgcn_s_setprio(0);
  }

  // epilogue: reduce l across lane-groups, normalize, un-transpose via Pw
  float lt = l_run;
  lt += __shfl_xor(lt, 16);
  lt += __shfl_xor(lt, 32);
  float inv = 1.f / lt;
  {
    char* pb = PwB + l15 * 128;
#pragma unroll
    for (int g = 0; g < 4; ++g) {
      const int boff = (g * 32 + lg * 8) ^ xorv;
      *(uint32_t*)(pb + boff) = pack2bf(acc[g][0] * inv, acc[g][1] * inv);
      *(uint32_t*)(pb + boff + 4) = pack2bf(acc[g][2] * inv, acc[g][3] * inv);
    }
  }
#pragma unroll
  for (int i = 0; i < 2; ++i) {
    const int rl = i * 8 + (lane >> 3);  // 0..15
    const int ch = lane & 7;
    u16x8 vv = *(const u16x8*)(PwB + rl * 128 + ((ch * 16) ^ ((rl & 7) << 4)));
    *(u16x8*)(&O[(size_t)(b * TSEQ + qrow + rl) * CDIM + h * DHEAD + ch * 8]) = vv;
  }
}

// ---------------- launch ----------------

extern "C" void kernel_launch(void* const* d_in, const int* in_sizes, int n_in,
                              void* d_out, int out_size, void* d_ws, size_t ws_size,
                              hipStream_t stream) {
  const float* x  = (const float*)d_in[0];
  const float* wq = (const float*)d_in[1];
  const float* bq = (const float*)d_in[2];
  const float* wk = (const float*)d_in[3];
  const float* bk = (const float*)d_in[4];
  const float* wv = (const float*)d_in[5];
  const float* bv = (const float*)d_in[6];
  const float* wo = (const float*)d_in[7];
  const float* bo = (const float*)d_in[8];
  float* out = (float*)d_out;

  char* ws = (char*)d_ws;
  u16*  xb      = (u16*)(ws);                 // 8MB; dead after QKV GEMM
  u16*  Vtg     = (u16*)(ws);                 // aliases xb (written after)
  u16*  wqkvT   = (u16*)(ws + (8ll << 20));
  u16*  woT     = (u16*)(ws + (14ll << 20));
  u16*  QKV     = (u16*)(ws + (16ll << 20));
  u16*  Obuf    = (u16*)(ws + (40ll << 20));
  float* biasqkv = (float*)(ws + (48ll << 20));

  cast_x_kernel<<<(NROWS * CDIM / 4 + 255) / 256, 256, 0, stream>>>(x, xb, NROWS * CDIM / 4);
  {
    dim3 g(CDIM / 32, CDIM / 32, 4), blk(32, 8);
    transpose_cast_kernel<<<g, blk, 0, stream>>>(wq, wk, wv, wo, wqkvT, woT);
  }
  bias_concat_kernel<<<12, 256, 0, stream>>>(bq, bk, bv, biasqkv);
  gemm_bt_kernel<u16><<<(NROWS / 128) * ((3 * CDIM) / 128), 256, 0, stream>>>(
      xb, wqkvT, biasqkv, QKV, NROWS, 3 * CDIM, CDIM, NROWS / 128);
  {
    dim3 g(TSEQ / 32, DHEAD / 32, BATCH * NHEAD), blk(32, 8);
    vtrans_kernel<<<g, blk, 0, stream>>>(QKV, Vtg);
  }
  attn_kernel<<<512, 512, 0, stream>>>(QKV, Vtg, Obuf);
  gemm_bt_kernel<float><<<(NROWS / 128) * (CDIM / 128), 256, 0, stream>>>(
      Obuf, woT, bo, out, NROWS, CDIM, CDIM, NROWS / 128);
}